// Round 6
// baseline (181.803 us; speedup 1.0000x reference)
//
#include <hip/hip_runtime.h>
#include <hip/hip_bf16.h>
#include <math.h>

// ---------------------------------------------------------------------------
// MoE gate via fp16 hi/lo split MFMA, 3 products (validated round 5):
//   x = xh + xl/2048,  W*64 = wh + wl/2048
//   logit = ( xh·wh + (xh·wl + xl·wh)/2048 ) / 64
// Round 6 perf restructure (numerics/routing identical to round 5):
//   - BM=128,BN=128, wave tile 64x64 (4x4 of 16x16x32 f16 MFMA)
//   - B operands read DIRECTLY from global (frag-major pre-tiled W, L2-
//     resident 458KB/chunk) -> LDS holds only A (32KB, 2 blocks/CU)
//   - KS=8 K-split, fp64 combine in routing (round-5-validated margin)
// ---------------------------------------------------------------------------

typedef _Float16 f16x8 __attribute__((ext_vector_type(8)));
typedef float    f32x4 __attribute__((ext_vector_type(4)));

__device__ __forceinline__ unsigned short f2h(float f) {
  _Float16 h = (_Float16)f;                       // v_cvt_f16_f32, RTN
  return __builtin_bit_cast(unsigned short, h);
}
__device__ __forceinline__ float h2f(unsigned short b) {
  return (float)__builtin_bit_cast(_Float16, b);
}

// ---------------------------------------------------------------------------
// W [256][7168] fp32 -> Whi/Wlo fp16, FRAGMENT-MAJOR tiles:
// tile (bn in 0..1, s in 0..111) holds rows r=0..127, K=64.
// element (r,k): gi=(k&63)>>3 (k-granule), stored at
//   tile*8192 + gi*1024 + r*8 + (k&7)   (ushorts)
// A 16-lane MFMA fragment read = 16 consecutive rows at one gi
// = 256B contiguous -> coalesced global load, no LDS needed for B.
// Whi = fp16(64*W); Wlo = fp16((64*W - Whi) * 2048).
// ---------------------------------------------------------------------------
__global__ __launch_bounds__(256) void convert_w(
    const float* __restrict__ W,
    unsigned short* __restrict__ Whi, unsigned short* __restrict__ Wlo)
{
  const int e = blockIdx.x;           // expert 0..255
  const int t = threadIdx.x;          // 0..255, use 224
  if (t >= 224) return;
  const int r = e & 127, bn = e >> 7;
  const float* src = W + (size_t)e * 7168 + t * 32;
  #pragma unroll
  for (int q = 0; q < 4; ++q) {
    const int k = t * 32 + q * 8;
    const int s = k >> 6, gi = (k & 63) >> 3;
    const size_t base = (size_t)(bn * 112 + s) * 8192
                      + (size_t)gi * 1024 + (size_t)r * 8;
    unsigned int hw[4], lw[4];
    #pragma unroll
    for (int p = 0; p < 4; ++p) {
      float f0 = src[q * 8 + 2 * p] * 64.0f;
      float f1 = src[q * 8 + 2 * p + 1] * 64.0f;
      unsigned short h0 = f2h(f0), h1 = f2h(f1);
      unsigned short l0 = f2h((f0 - h2f(h0)) * 2048.0f);
      unsigned short l1 = f2h((f1 - h2f(h1)) * 2048.0f);
      hw[p] = (unsigned)h0 | ((unsigned)h1 << 16);
      lw[p] = (unsigned)l0 | ((unsigned)l1 << 16);
    }
    *(uint4*)(Whi + base) = make_uint4(hw[0], hw[1], hw[2], hw[3]);
    *(uint4*)(Wlo + base) = make_uint4(lw[0], lw[1], lw[2], lw[3]);
  }
}

// ---------------------------------------------------------------------------
// GEMM: BM=128, BN=128, BK=64, K-split KS (grid.z). 256 threads = 4 waves
// (2x2), wave tile 64x64 = 4x4 frags of 16x16x32 f16 MFMA, 3 products.
// A: fp32 global -> reg -> fp16 hi/lo -> swizzled LDS (only A in LDS).
// B: fragment-direct global loads from frag-major Whi/Wlo tiles (L2-hot).
// ---------------------------------------------------------------------------
__global__ __launch_bounds__(256, 2) void gate_gemm(
    const float* __restrict__ X,
    const unsigned short* __restrict__ Whi,
    const unsigned short* __restrict__ Wlo,
    float* __restrict__ Spart, int D, int TILES)
{
  __shared__ char lds[32768];
  char* Ahi = lds;                    // 128 rows x 128B = 16KB
  char* Alo = lds + 16384;

  const int bn = blockIdx.x, bm = blockIdx.y, ks = blockIdx.z;
  const int tid = threadIdx.x, lane = tid & 63, wid = tid >> 6;
  const int wm = wid >> 1, wn = wid & 1;    // 2x2 wave grid
  const int TM = bm * 128;
  const int k0base = ks * TILES * 64;       // K-chunk start

  // A staging: 2 threads per row, 32 contiguous fp32 each (4 granules)
  const int srow = tid >> 1, skq = tid & 1;
  const float* xsrc = X + (size_t)(TM + srow) * D + k0base + skq * 32;
  int aw[4];
  #pragma unroll
  for (int g = 0; g < 4; ++g) {
    const int gi = skq * 4 + g;
    aw[g] = srow * 128 + ((gi ^ (srow & 7)) * 16);
  }

  const unsigned short* wh_tile = Whi + (size_t)(bn * 112 + ks * TILES) * 8192;
  const unsigned short* wl_tile = Wlo + (size_t)(bn * 112 + ks * TILES) * 8192;

  f32x4 acc1[4][4], acc2[4][4];
  #pragma unroll
  for (int m = 0; m < 4; ++m)
    #pragma unroll
    for (int n = 0; n < 4; ++n) { acc1[m][n] = (f32x4)0.0f; acc2[m][n] = (f32x4)0.0f; }

  float4 pa[8];
  #pragma unroll
  for (int i = 0; i < 8; ++i) pa[i] = *(const float4*)(xsrc + i * 4);

  for (int s = 0; s < TILES; ++s) {
    // convert prefetched A (32 fp32 -> 32 hi + 32 lo fp16, packed)
    unsigned int hw[16], lw[16];
    #pragma unroll
    for (int q = 0; q < 16; ++q) {
      float f0 = ((const float*)pa)[2 * q], f1 = ((const float*)pa)[2 * q + 1];
      unsigned short h0 = f2h(f0), h1 = f2h(f1);
      unsigned short l0 = f2h((f0 - h2f(h0)) * 2048.0f);
      unsigned short l1 = f2h((f1 - h2f(h1)) * 2048.0f);
      hw[q] = (unsigned)h0 | ((unsigned)h1 << 16);
      lw[q] = (unsigned)l0 | ((unsigned)l1 << 16);
    }

    __syncthreads();   // previous iteration's A reads complete

    // stage A (swizzled ds_write_b128: 4 hi + 4 lo)
    #pragma unroll
    for (int g = 0; g < 4; ++g) {
      *(uint4*)(Ahi + aw[g]) = make_uint4(hw[4*g], hw[4*g+1], hw[4*g+2], hw[4*g+3]);
      *(uint4*)(Alo + aw[g]) = make_uint4(lw[4*g], lw[4*g+1], lw[4*g+2], lw[4*g+3]);
    }

    __syncthreads();   // A tile visible

    // prefetch next A tile (hides under MFMA)
    if (s < TILES - 1) {
      #pragma unroll
      for (int i = 0; i < 8; ++i)
        pa[i] = *(const float4*)(xsrc + (s + 1) * 64 + i * 4);
    }

    const unsigned short* wh = wh_tile + (size_t)s * 8192;
    const unsigned short* wl = wl_tile + (size_t)s * 8192;

    #pragma unroll
    for (int ksub = 0; ksub < 2; ++ksub) {
      const int gi = ksub * 4 + (lane >> 4);
      // B fragments: direct, coalesced global loads (L2-resident tiles)
      f16x8 bh[4], bl[4];
      #pragma unroll
      for (int n = 0; n < 4; ++n) {
        const int row = wn * 64 + n * 16 + (lane & 15);
        const size_t off = (size_t)gi * 1024 + (size_t)row * 8;
        bh[n] = *(const f16x8*)(wh + off);
        bl[n] = *(const f16x8*)(wl + off);
      }
      // A fragments from LDS (validated swizzle pattern)
      f16x8 ah[4], al[4];
      #pragma unroll
      for (int m = 0; m < 4; ++m) {
        const int row = wm * 64 + m * 16 + (lane & 15);
        const int off = row * 128 + ((gi ^ (row & 7)) * 16);
        ah[m] = *(const f16x8*)(Ahi + off);
        al[m] = *(const f16x8*)(Alo + off);
      }
      #pragma unroll
      for (int m = 0; m < 4; ++m)
        #pragma unroll
        for (int n = 0; n < 4; ++n) {
          acc1[m][n] = __builtin_amdgcn_mfma_f32_16x16x32_f16(ah[m], bh[n], acc1[m][n], 0, 0, 0);
          acc2[m][n] = __builtin_amdgcn_mfma_f32_16x16x32_f16(ah[m], bl[n], acc2[m][n], 0, 0, 0);
          acc2[m][n] = __builtin_amdgcn_mfma_f32_16x16x32_f16(al[m], bh[n], acc2[m][n], 0, 0, 0);
        }
    }
  }

  // epilogue: logit partial = (acc1 + acc2/2048) / 64
  // C/D layout: col=lane&15, row=(lane>>4)*4+reg
  float* Sp = Spart + (size_t)ks * 8192 * 256;
  #pragma unroll
  for (int m = 0; m < 4; ++m)
    #pragma unroll
    for (int n = 0; n < 4; ++n)
      #pragma unroll
      for (int r = 0; r < 4; ++r) {
        const int t = TM + wm * 64 + m * 16 + (lane >> 4) * 4 + r;
        const int e = bn * 128 + wn * 64 + n * 16 + (lane & 15);
        Sp[(size_t)t * 256 + e] =
            (acc1[m][n][r] + acc2[m][n][r] * (1.0f / 2048.0f)) * (1.0f / 64.0f);
      }
}

// ---------------------------------------------------------------------------
// Routing: one wave per token. logit = sum of KS fp32 partials in DOUBLE
// (exact); scores = sigmoid (fp32); then grouped top-k (8 groups, top-2
// group score, top-4 groups, top-8 experts, renorm * 2.5).
// ---------------------------------------------------------------------------
__global__ __launch_bounds__(256) void gate_routing(
    const float* __restrict__ Spart, int KS,
    const float* __restrict__ bias,
    float* __restrict__ outw, float* __restrict__ outi, int T)
{
  const int lane = threadIdx.x & 63;
  const int wave = threadIdx.x >> 6;
  const int t = blockIdx.x * 4 + wave;
  if (t >= T) return;

  double l[4] = {0.0, 0.0, 0.0, 0.0};
  for (int ks = 0; ks < KS; ++ks) {
    float4 p = *(const float4*)(Spart + (size_t)ks * T * 256
                                + (size_t)t * 256 + lane * 4);
    l[0] += (double)p.x; l[1] += (double)p.y;
    l[2] += (double)p.z; l[3] += (double)p.w;
  }

  float4 bi = *(const float4*)(bias + lane * 4);
  float orig[4], s[4];
  #pragma unroll
  for (int u = 0; u < 4; ++u)
    orig[u] = 1.0f / (1.0f + expf(-(float)l[u]));
  s[0] = orig[0] + bi.x; s[1] = orig[1] + bi.y;
  s[2] = orig[2] + bi.z; s[3] = orig[3] + bi.w;

  // per-lane top-2 of its 4 biased scores
  float m1 = -INFINITY, m2 = -INFINITY;
  #pragma unroll
  for (int u = 0; u < 4; ++u) {
    float v = s[u];
    if (v > m1) { m2 = m1; m1 = v; }
    else if (v > m2) { m2 = v; }
  }
  // merge top-2 across the 8 lanes of the group
  #pragma unroll
  for (int off = 1; off < 8; off <<= 1) {
    float o1 = __shfl_xor(m1, off, 64);
    float o2 = __shfl_xor(m2, off, 64);
    if (o1 > m1) { m2 = fmaxf(m1, o2); m1 = o1; }
    else         { m2 = fmaxf(m2, o1); }
  }
  const float gscore = m1 + m2;

  const int g = lane >> 3;
  int rank = 0;
  #pragma unroll
  for (int j = 0; j < 8; ++j) {
    float gs = __shfl(gscore, j * 8, 64);
    rank += (gs > gscore || (gs == gscore && j < g)) ? 1 : 0;
  }
  if (rank >= 4) { s[0] = s[1] = s[2] = s[3] = -INFINITY; }

  float wsum = 0.0f, sel_w = 0.0f;
  int sel_i = 0;
  #pragma unroll
  for (int it = 0; it < 8; ++it) {
    float bv = s[0]; int bu = 0;
    #pragma unroll
    for (int u = 1; u < 4; ++u)
      if (s[u] > bv) { bv = s[u]; bu = u; }
    float v = bv;
    int ix = lane * 4 + bu;
    float og = orig[bu];
    #pragma unroll
    for (int off = 1; off < 64; off <<= 1) {
      float ov  = __shfl_xor(v,  off, 64);
      int   oix = __shfl_xor(ix, off, 64);
      float oog = __shfl_xor(og, off, 64);
      if (ov > v || (ov == v && oix < ix)) { v = ov; ix = oix; og = oog; }
    }
    if (lane == it) { sel_w = og; sel_i = ix; }
    wsum += og;
    if ((ix >> 2) == lane) s[ix & 3] = -INFINITY;
  }

  if (lane < 8) {
    outw[(size_t)t * 8 + lane] = sel_w / wsum * 2.5f;
    outi[(size_t)t * 8 + lane] = (float)sel_i;
  }
}

extern "C" void kernel_launch(void* const* d_in, const int* in_sizes, int n_in,
                              void* d_out, int out_size, void* d_ws, size_t ws_size,
                              hipStream_t stream) {
  const float* x = (const float*)d_in[0];
  const float* w = (const float*)d_in[1];
  const float* b = (const float*)d_in[2];
  const int E = in_sizes[2];                  // 256
  const int D = in_sizes[1] / E;              // 7168
  const int T = in_sizes[0] / D;              // 8192

  unsigned short* Whi = (unsigned short*)d_ws;                       // 3.67 MB
  unsigned short* Wlo = (unsigned short*)((char*)d_ws + (4u << 20)); // 3.67 MB
  float* Spart = (float*)((char*)d_ws + (8u << 20));                 // KS x 8 MB

  // adaptive K-split: largest of {8,4,2} that fits the workspace
  const size_t per_part = (size_t)T * E * 4;
  int KS = 2;
  if (ws_size >= (8u << 20) + 8 * per_part) KS = 8;
  else if (ws_size >= (8u << 20) + 4 * per_part) KS = 4;
  const int TILES = D / (64 * KS);            // 14 for KS=8

  float* outw = (float*)d_out;
  float* outi = outw + (size_t)T * 8;

  convert_w<<<E, 256, 0, stream>>>(w, Whi, Wlo);
  gate_gemm<<<dim3(2, T / 128, KS), 256, 0, stream>>>(x, Whi, Wlo, Spart, D, TILES);
  gate_routing<<<(T + 3) / 4, 256, 0, stream>>>(Spart, KS, b, outw, outi, T);
}

// Round 7
// 151.479 us; speedup vs baseline: 1.2002x; 1.2002x over previous
//
#include <hip/hip_runtime.h>
#include <hip/hip_bf16.h>
#include <math.h>

// ---------------------------------------------------------------------------
// MoE gate via fp16 hi/lo split MFMA, 3 products (validated round 5):
//   x = xh + xl/2048,  W*64 = wh + wl/2048
//   logit = ( xh·wh + (xh·wl + xl·wh)/2048 ) / 64
// Round 7: back to LDS-staged B (round-6 B-from-global regressed), but with
// a pipelined 2-phase schedule: double-buffered LDS, stage(s+1) ISSUED
// BEFORE compute(s), single barrier per K-step. BM=BN=128, BK=32, KS=8.
// Numerics / routing / fp64 combine identical to round 5 (passed).
// ---------------------------------------------------------------------------

typedef _Float16 f16x8 __attribute__((ext_vector_type(8)));
typedef float    f32x4 __attribute__((ext_vector_type(4)));

__device__ __forceinline__ void glds16(const void* g, void* l) {
  __builtin_amdgcn_global_load_lds(
      (const __attribute__((address_space(1))) void*)g,
      (__attribute__((address_space(3))) void*)l, 16, 0, 0);
}

__device__ __forceinline__ unsigned short f2h(float f) {
  _Float16 h = (_Float16)f;                       // v_cvt_f16_f32, RTN
  return __builtin_bit_cast(unsigned short, h);
}
__device__ __forceinline__ float h2f(unsigned short b) {
  return (float)__builtin_bit_cast(_Float16, b);
}

// swizzle: 64B rows, 4 granules of 16B; spreads 16-row fragment reads
// across all banks (>=2-way only, free).  Same formula on write and read.
__device__ __forceinline__ int swz(int gi, int row) {
  return gi ^ (row & 3) ^ ((row >> 2) & 3);
}

// ---------------------------------------------------------------------------
// W [256][7168] fp32 -> Whi/Wlo fp16, tiled pre-swizzled layout (BK=32):
// tile (bn in 0..1, s in 0..223) = 128 rows x 32 f16 = 4096 ushorts (8KB).
// element (r,k): gi=(k&31)>>3, addr = tile*4096 + r*32 + swz(gi,r)*8 + (k&7)
// Whi = fp16(64*W); Wlo = fp16((64*W - Whi) * 2048).
// ---------------------------------------------------------------------------
__global__ __launch_bounds__(256) void convert_w(
    const float* __restrict__ W,
    unsigned short* __restrict__ Whi, unsigned short* __restrict__ Wlo)
{
  const int e = blockIdx.x;           // expert 0..255
  const int t = threadIdx.x;          // 0..255, use 224 (one BK=32 tile each)
  if (t >= 224) return;
  const int r = e & 127, bn = e >> 7;
  const float* src = W + (size_t)e * 7168 + t * 32;
  const size_t tbase = (size_t)(bn * 224 + t) * 4096 + (size_t)r * 32;
  #pragma unroll
  for (int g = 0; g < 4; ++g) {       // granule gi = g, k = g*8..g*8+7
    unsigned int hw[4], lw[4];
    #pragma unroll
    for (int p = 0; p < 4; ++p) {
      float f0 = src[g * 8 + 2 * p] * 64.0f;
      float f1 = src[g * 8 + 2 * p + 1] * 64.0f;
      unsigned short h0 = f2h(f0), h1 = f2h(f1);
      unsigned short l0 = f2h((f0 - h2f(h0)) * 2048.0f);
      unsigned short l1 = f2h((f1 - h2f(h1)) * 2048.0f);
      hw[p] = (unsigned)h0 | ((unsigned)h1 << 16);
      lw[p] = (unsigned)l0 | ((unsigned)l1 << 16);
    }
    const size_t base = tbase + (size_t)(swz(g, r) * 8);
    *(uint4*)(Whi + base) = make_uint4(hw[0], hw[1], hw[2], hw[3]);
    *(uint4*)(Wlo + base) = make_uint4(lw[0], lw[1], lw[2], lw[3]);
  }
}

// ---------------------------------------------------------------------------
// GEMM: BM=128, BN=128, BK=32, K-split KS (grid.z). 256 threads = 4 waves
// (2x2), wave tile 64x64 = 4x4 frags of 16x16x32 f16 MFMA, 3 products.
// Double-buffered LDS (2 x 32KB). Per iter: issue glds B(s+1) + load
// A(s+2) regs -> compute buf[cur] -> convert/ds_write A(s+1) -> barrier.
// ---------------------------------------------------------------------------
__global__ __launch_bounds__(256, 2) void gate_gemm(
    const float* __restrict__ X,
    const unsigned short* __restrict__ Whi,
    const unsigned short* __restrict__ Wlo,
    float* __restrict__ Spart, int D, int TILES)
{
  __shared__ char lds[65536];
  // buffer b at b*32768: Ahi +0, Alo +8192, Bhi +16384, Blo +24576

  const int bn = blockIdx.x, bm = blockIdx.y, ks = blockIdx.z;
  const int tid = threadIdx.x, lane = tid & 63, wid = tid >> 6;
  const int wm = wid >> 1, wn = wid & 1;    // 2x2 wave grid
  const int TM = bm * 128;
  const int k0base = ks * TILES * 32;       // K-chunk start

  // A staging: 2 threads per row, 16 contiguous fp32 each (granules 2*skq..+1)
  const int srow = tid >> 1, skq = tid & 1;
  const float* xsrc = X + (size_t)(TM + srow) * D + k0base + skq * 16;
  const int aw0 = srow * 64 + swz(skq * 2 + 0, srow) * 16;   // byte offsets
  const int aw1 = srow * 64 + swz(skq * 2 + 1, srow) * 16;

  const unsigned short* wh_tile = Whi + (size_t)(bn * 224 + ks * TILES) * 4096;
  const unsigned short* wl_tile = Wlo + (size_t)(bn * 224 + ks * TILES) * 4096;

  f32x4 acc1[4][4], acc2[4][4];
  #pragma unroll
  for (int m = 0; m < 4; ++m)
    #pragma unroll
    for (int n = 0; n < 4; ++n) { acc1[m][n] = (f32x4)0.0f; acc2[m][n] = (f32x4)0.0f; }

  // fragment read offsets (byte), fixed per lane
  int aro[4], bro[4];
  const int gi = lane >> 4;
  #pragma unroll
  for (int m = 0; m < 4; ++m) {
    const int row = wm * 64 + m * 16 + (lane & 15);
    aro[m] = row * 64 + swz(gi, row) * 16;
  }
  #pragma unroll
  for (int n = 0; n < 4; ++n) {
    const int row = wn * 64 + n * 16 + (lane & 15);
    bro[n] = row * 64 + swz(gi, row) * 16;
  }

  // ---- prologue: stage tile 0 into buf0; preload A(1) ----
  float4 pa[4], pb[4];
  #pragma unroll
  for (int i = 0; i < 4; ++i) pa[i] = *(const float4*)(xsrc + i * 4);
  {
    char* Bh = lds + 16384; char* Bl = lds + 24576;
    #pragma unroll
    for (int i = 0; i < 2; ++i) {
      const int c = wid * 2 + i;          // chunk 0..7, wave-uniform
      glds16(wh_tile + c * 512 + lane * 8, Bh + c * 1024);
      glds16(wl_tile + c * 512 + lane * 8, Bl + c * 1024);
    }
    // convert + write A(0)
    unsigned int hw[8], lw[8];
    #pragma unroll
    for (int q = 0; q < 8; ++q) {
      float f0 = ((const float*)pa)[2 * q], f1 = ((const float*)pa)[2 * q + 1];
      unsigned short h0 = f2h(f0), h1 = f2h(f1);
      unsigned short l0 = f2h((f0 - h2f(h0)) * 2048.0f);
      unsigned short l1 = f2h((f1 - h2f(h1)) * 2048.0f);
      hw[q] = (unsigned)h0 | ((unsigned)h1 << 16);
      lw[q] = (unsigned)l0 | ((unsigned)l1 << 16);
    }
    char* Ahi = lds; char* Alo = lds + 8192;
    *(uint4*)(Ahi + aw0) = make_uint4(hw[0], hw[1], hw[2], hw[3]);
    *(uint4*)(Ahi + aw1) = make_uint4(hw[4], hw[5], hw[6], hw[7]);
    *(uint4*)(Alo + aw0) = make_uint4(lw[0], lw[1], lw[2], lw[3]);
    *(uint4*)(Alo + aw1) = make_uint4(lw[4], lw[5], lw[6], lw[7]);
  }
  if (TILES > 1) {
    #pragma unroll
    for (int i = 0; i < 4; ++i) pa[i] = *(const float4*)(xsrc + 32 + i * 4);
  }
  __syncthreads();    // buf0 staged; pa holds A(1)

  int cur = 0;
  for (int s = 0; s < TILES; ++s) {
    const int nxt = cur ^ 1;
    char* base_c = lds + cur * 32768;
    char* base_n = lds + nxt * 32768;

    // issue next-tile B staging (async, lands during compute)
    if (s + 1 < TILES) {
      const unsigned short* wh = wh_tile + (size_t)(s + 1) * 4096;
      const unsigned short* wl = wl_tile + (size_t)(s + 1) * 4096;
      char* Bh = base_n + 16384; char* Bl = base_n + 24576;
      #pragma unroll
      for (int i = 0; i < 2; ++i) {
        const int c = wid * 2 + i;
        glds16(wh + c * 512 + lane * 8, Bh + c * 1024);
        glds16(wl + c * 512 + lane * 8, Bl + c * 1024);
      }
    }
    // issue A loads for tile s+2 (lands during compute)
    if (s + 2 < TILES) {
      #pragma unroll
      for (int i = 0; i < 4; ++i)
        pb[i] = *(const float4*)(xsrc + (size_t)(s + 2) * 32 + i * 4);
    }

    // compute from buf[cur]
    {
      const char* Ahi = base_c;          const char* Alo = base_c + 8192;
      const char* Bh  = base_c + 16384;  const char* Bl  = base_c + 24576;
      f16x8 ah[4], al[4], bh[4], bl[4];
      #pragma unroll
      for (int m = 0; m < 4; ++m) {
        ah[m] = *(const f16x8*)(Ahi + aro[m]);
        al[m] = *(const f16x8*)(Alo + aro[m]);
      }
      #pragma unroll
      for (int n = 0; n < 4; ++n) {
        bh[n] = *(const f16x8*)(Bh + bro[n]);
        bl[n] = *(const f16x8*)(Bl + bro[n]);
      }
      #pragma unroll
      for (int m = 0; m < 4; ++m)
        #pragma unroll
        for (int n = 0; n < 4; ++n) {
          acc1[m][n] = __builtin_amdgcn_mfma_f32_16x16x32_f16(ah[m], bh[n], acc1[m][n], 0, 0, 0);
          acc2[m][n] = __builtin_amdgcn_mfma_f32_16x16x32_f16(ah[m], bl[n], acc2[m][n], 0, 0, 0);
          acc2[m][n] = __builtin_amdgcn_mfma_f32_16x16x32_f16(al[m], bh[n], acc2[m][n], 0, 0, 0);
        }
    }

    // convert + ds_write A(s+1) into buf[nxt] (pa loaded 1-2 iters ago)
    if (s + 1 < TILES) {
      unsigned int hw[8], lw[8];
      #pragma unroll
      for (int q = 0; q < 8; ++q) {
        float f0 = ((const float*)pa)[2 * q], f1 = ((const float*)pa)[2 * q + 1];
        unsigned short h0 = f2h(f0), h1 = f2h(f1);
        unsigned short l0 = f2h((f0 - h2f(h0)) * 2048.0f);
        unsigned short l1 = f2h((f1 - h2f(h1)) * 2048.0f);
        hw[q] = (unsigned)h0 | ((unsigned)h1 << 16);
        lw[q] = (unsigned)l0 | ((unsigned)l1 << 16);
      }
      char* Ahi = base_n; char* Alo = base_n + 8192;
      *(uint4*)(Ahi + aw0) = make_uint4(hw[0], hw[1], hw[2], hw[3]);
      *(uint4*)(Ahi + aw1) = make_uint4(hw[4], hw[5], hw[6], hw[7]);
      *(uint4*)(Alo + aw0) = make_uint4(lw[0], lw[1], lw[2], lw[3]);
      *(uint4*)(Alo + aw1) = make_uint4(lw[4], lw[5], lw[6], lw[7]);
      #pragma unroll
      for (int i = 0; i < 4; ++i) pa[i] = pb[i];
    }

    __syncthreads();   // single barrier per K-step: buf[nxt] ready
    cur = nxt;
  }

  // epilogue: logit partial = (acc1 + acc2/2048) / 64
  // C/D layout: col=lane&15, row=(lane>>4)*4+reg
  float* Sp = Spart + (size_t)ks * 8192 * 256;
  #pragma unroll
  for (int m = 0; m < 4; ++m)
    #pragma unroll
    for (int n = 0; n < 4; ++n)
      #pragma unroll
      for (int r = 0; r < 4; ++r) {
        const int t = TM + wm * 64 + m * 16 + (lane >> 4) * 4 + r;
        const int e = bn * 128 + wn * 64 + n * 16 + (lane & 15);
        Sp[(size_t)t * 256 + e] =
            (acc1[m][n][r] + acc2[m][n][r] * (1.0f / 2048.0f)) * (1.0f / 64.0f);
      }
}

// ---------------------------------------------------------------------------
// Routing: one wave per token. logit = sum of KS fp32 partials in DOUBLE
// (exact); scores = sigmoid (fp32); then grouped top-k (8 groups, top-2
// group score, top-4 groups, top-8 experts, renorm * 2.5).
// ---------------------------------------------------------------------------
__global__ __launch_bounds__(256) void gate_routing(
    const float* __restrict__ Spart, int KS,
    const float* __restrict__ bias,
    float* __restrict__ outw, float* __restrict__ outi, int T)
{
  const int lane = threadIdx.x & 63;
  const int wave = threadIdx.x >> 6;
  const int t = blockIdx.x * 4 + wave;
  if (t >= T) return;

  double l[4] = {0.0, 0.0, 0.0, 0.0};
  for (int ks = 0; ks < KS; ++ks) {
    float4 p = *(const float4*)(Spart + (size_t)ks * T * 256
                                + (size_t)t * 256 + lane * 4);
    l[0] += (double)p.x; l[1] += (double)p.y;
    l[2] += (double)p.z; l[3] += (double)p.w;
  }

  float4 bi = *(const float4*)(bias + lane * 4);
  float orig[4], s[4];
  #pragma unroll
  for (int u = 0; u < 4; ++u)
    orig[u] = 1.0f / (1.0f + expf(-(float)l[u]));
  s[0] = orig[0] + bi.x; s[1] = orig[1] + bi.y;
  s[2] = orig[2] + bi.z; s[3] = orig[3] + bi.w;

  // per-lane top-2 of its 4 biased scores
  float m1 = -INFINITY, m2 = -INFINITY;
  #pragma unroll
  for (int u = 0; u < 4; ++u) {
    float v = s[u];
    if (v > m1) { m2 = m1; m1 = v; }
    else if (v > m2) { m2 = v; }
  }
  // merge top-2 across the 8 lanes of the group
  #pragma unroll
  for (int off = 1; off < 8; off <<= 1) {
    float o1 = __shfl_xor(m1, off, 64);
    float o2 = __shfl_xor(m2, off, 64);
    if (o1 > m1) { m2 = fmaxf(m1, o2); m1 = o1; }
    else         { m2 = fmaxf(m2, o1); }
  }
  const float gscore = m1 + m2;

  const int g = lane >> 3;
  int rank = 0;
  #pragma unroll
  for (int j = 0; j < 8; ++j) {
    float gs = __shfl(gscore, j * 8, 64);
    rank += (gs > gscore || (gs == gscore && j < g)) ? 1 : 0;
  }
  if (rank >= 4) { s[0] = s[1] = s[2] = s[3] = -INFINITY; }

  float wsum = 0.0f, sel_w = 0.0f;
  int sel_i = 0;
  #pragma unroll
  for (int it = 0; it < 8; ++it) {
    float bv = s[0]; int bu = 0;
    #pragma unroll
    for (int u = 1; u < 4; ++u)
      if (s[u] > bv) { bv = s[u]; bu = u; }
    float v = bv;
    int ix = lane * 4 + bu;
    float og = orig[bu];
    #pragma unroll
    for (int off = 1; off < 64; off <<= 1) {
      float ov  = __shfl_xor(v,  off, 64);
      int   oix = __shfl_xor(ix, off, 64);
      float oog = __shfl_xor(og, off, 64);
      if (ov > v || (ov == v && oix < ix)) { v = ov; ix = oix; og = oog; }
    }
    if (lane == it) { sel_w = og; sel_i = ix; }
    wsum += og;
    if ((ix >> 2) == lane) s[ix & 3] = -INFINITY;
  }

  if (lane < 8) {
    outw[(size_t)t * 8 + lane] = sel_w / wsum * 2.5f;
    outi[(size_t)t * 8 + lane] = (float)sel_i;
  }
}

extern "C" void kernel_launch(void* const* d_in, const int* in_sizes, int n_in,
                              void* d_out, int out_size, void* d_ws, size_t ws_size,
                              hipStream_t stream) {
  const float* x = (const float*)d_in[0];
  const float* w = (const float*)d_in[1];
  const float* b = (const float*)d_in[2];
  const int E = in_sizes[2];                  // 256
  const int D = in_sizes[1] / E;              // 7168
  const int T = in_sizes[0] / D;              // 8192

  unsigned short* Whi = (unsigned short*)d_ws;                       // 3.67 MB
  unsigned short* Wlo = (unsigned short*)((char*)d_ws + (4u << 20)); // 3.67 MB
  float* Spart = (float*)((char*)d_ws + (8u << 20));                 // KS x 8 MB

  // adaptive K-split: largest of {8,4,2} that fits the workspace
  const size_t per_part = (size_t)T * E * 4;
  int KS = 2;
  if (ws_size >= (8u << 20) + 8 * per_part) KS = 8;
  else if (ws_size >= (8u << 20) + 4 * per_part) KS = 4;
  const int TILES = D / (32 * KS);            // 28 for KS=8

  float* outw = (float*)d_out;
  float* outi = outw + (size_t)T * 8;

  convert_w<<<E, 256, 0, stream>>>(w, Whi, Wlo);
  gate_gemm<<<dim3(2, T / 128, KS), 256, 0, stream>>>(x, Whi, Wlo, Spart, D, TILES);
  gate_routing<<<(T + 3) / 4, 256, 0, stream>>>(Spart, KS, b, outw, outi, T);
}